// Round 1
// baseline (357.706 us; speedup 1.0000x reference)
//
#include <hip/hip_runtime.h>
#include <hip/hip_bf16.h>

// PLoss fused kernel, round 1.
// Design:
//  - One fused pass over rows (memory-bound target: 205 MB read @ ~6.3 TB/s ~ 33 us).
//  - Tile = 32 rows, block = 256 threads (4 waves). Each wave owns 32 proto columns.
//  - Prototypes (128x128 fp32 = 64 KB) are preloaded ONCE per block into per-lane
//    MFMA B-fragments (bf16, 32 VGPRs/lane) + 0.5*||p||^2 in fp32. No LDS for P.
//  - Stage: 8 threads/row load 16 fp32 each (4x float4, coalesced), compute
//    two-pass max/sumexp in registers, shuffle-combine (xor 1,2,4) -> lse fp32.
//    Convert to bf16 (RNE), write row-major LDS tile, stride 136 bf16 (2-way bank
//    aliasing = free per m136; rows stay 16B-aligned for ds_read_b128).
//  - MFMA 16x16x32 bf16: per wave 2 m-tiles x 2 n-tiles x 4 k-steps = 16 mfma.
//  - argmin: score = 0.5||p||^2 - dot (x2 drops out, sqrt monotone). Reduce over
//    16 lanes sharing a row (shuffle-xor 1,2,4,8), then across 4 waves via LDS.
//  - NLL uses bf16 x[label_eff] (rounding is unbiased, mean error ~1e-5) and fp32 lse.
//  - Mean: per-thread accumulate -> wave-0 shuffle reduce -> float atomicAdd to ws,
//    finalize kernel divides by N. ws zeroed with hipMemsetAsync (capture-safe).

#define C_DIM 128
#define TILE_ROWS 32
#define NTHREADS 256
#define XSTRIDE 136   // bf16 elems per LDS row: 128 + 8 pad (16B-aligned rows)

typedef __bf16 bf16x8 __attribute__((ext_vector_type(8)));
typedef unsigned short ushort8 __attribute__((ext_vector_type(8)));
typedef float f32x4 __attribute__((ext_vector_type(4)));

union FragU { ushort8 u; bf16x8 b; };

__device__ __forceinline__ unsigned short f2bf(float f) {
    unsigned int u = __float_as_uint(f);
    u += 0x7fffu + ((u >> 16) & 1u);   // round-to-nearest-even
    return (unsigned short)(u >> 16);
}
__device__ __forceinline__ float bf2f(unsigned short h) {
    return __uint_as_float(((unsigned int)h) << 16);
}

extern "C" __global__ void __launch_bounds__(NTHREADS)
ploss_main(const float* __restrict__ x, const int* __restrict__ labels,
           const float* __restrict__ protos, const int* __restrict__ kptr,
           float* __restrict__ accum, int n_tiles)
{
    __shared__ __attribute__((aligned(16))) unsigned short x_lds[TILE_ROWS * XSTRIDE];
    __shared__ float lse_lds[TILE_ROWS];
    __shared__ float wmin_s[4][TILE_ROWS];
    __shared__ int   wmin_j[4][TILE_ROWS];

    const int tid  = threadIdx.x;
    const int lane = tid & 63;
    const int wave = tid >> 6;
    const int l15  = lane & 15;
    const int quad = lane >> 4;
    const int kk   = kptr[0];

    // ---- preload B fragments (protos, bf16) + 0.5*||p||^2 : once per block ----
    FragU bfrag[2][4];
    float p2h[2];
#pragma unroll
    for (int nt = 0; nt < 2; ++nt) {
        const int j = wave * 32 + nt * 16 + l15;
        const float* pr = protos + j * C_DIM;
        float s = 0.f;
#pragma unroll
        for (int c = 0; c < 32; c += 4) {
            float4 v = *(const float4*)(pr + quad * 32 + c);
            s += v.x*v.x + v.y*v.y + v.z*v.z + v.w*v.w;
        }
        s += __shfl_xor(s, 16);
        s += __shfl_xor(s, 32);
        p2h[nt] = 0.5f * s;
#pragma unroll
        for (int kt = 0; kt < 4; ++kt) {
            const float* pp = pr + kt * 32 + quad * 8;
            float4 v0 = *(const float4*)(pp);
            float4 v1 = *(const float4*)(pp + 4);
            FragU f;
            f.u[0]=f2bf(v0.x); f.u[1]=f2bf(v0.y); f.u[2]=f2bf(v0.z); f.u[3]=f2bf(v0.w);
            f.u[4]=f2bf(v1.x); f.u[5]=f2bf(v1.y); f.u[6]=f2bf(v1.z); f.u[7]=f2bf(v1.w);
            bfrag[nt][kt] = f;
        }
    }

    const int row_r = tid >> 3;   // 0..31: row within tile
    const int row_q = tid & 7;    // 0..7 : 16-elem chunk within row

    float nll_acc = 0.f;

    for (int tile = blockIdx.x; tile < n_tiles; tile += gridDim.x) {
        const long long row0 = (long long)tile * TILE_ROWS;
        __syncthreads();   // protect x_lds/lse from previous tile's readers

        // ---- stage: global load (fp32), softmax stats, bf16 -> LDS ----
        const float* xr = x + (row0 + row_r) * C_DIM + row_q * 16;
        float4 a0 = *(const float4*)(xr);
        float4 a1 = *(const float4*)(xr + 4);
        float4 a2 = *(const float4*)(xr + 8);
        float4 a3 = *(const float4*)(xr + 12);

        float m = fmaxf(fmaxf(fmaxf(a0.x,a0.y),fmaxf(a0.z,a0.w)),
                        fmaxf(fmaxf(a1.x,a1.y),fmaxf(a1.z,a1.w)));
        m = fmaxf(m, fmaxf(fmaxf(fmaxf(a2.x,a2.y),fmaxf(a2.z,a2.w)),
                           fmaxf(fmaxf(a3.x,a3.y),fmaxf(a3.z,a3.w))));
        float s = __expf(a0.x-m)+__expf(a0.y-m)+__expf(a0.z-m)+__expf(a0.w-m)
                + __expf(a1.x-m)+__expf(a1.y-m)+__expf(a1.z-m)+__expf(a1.w-m)
                + __expf(a2.x-m)+__expf(a2.y-m)+__expf(a2.z-m)+__expf(a2.w-m)
                + __expf(a3.x-m)+__expf(a3.y-m)+__expf(a3.z-m)+__expf(a3.w-m);
#pragma unroll
        for (int mask = 1; mask <= 4; mask <<= 1) {
            float mo = __shfl_xor(m, mask);
            float so = __shfl_xor(s, mask);
            float nm = fmaxf(m, mo);
            s = s * __expf(m - nm) + so * __expf(mo - nm);
            m = nm;
        }
        if (row_q == 0) lse_lds[row_r] = m + __logf(s);

        FragU w0, w1;
        w0.u[0]=f2bf(a0.x); w0.u[1]=f2bf(a0.y); w0.u[2]=f2bf(a0.z); w0.u[3]=f2bf(a0.w);
        w0.u[4]=f2bf(a1.x); w0.u[5]=f2bf(a1.y); w0.u[6]=f2bf(a1.z); w0.u[7]=f2bf(a1.w);
        w1.u[0]=f2bf(a2.x); w1.u[1]=f2bf(a2.y); w1.u[2]=f2bf(a2.z); w1.u[3]=f2bf(a2.w);
        w1.u[4]=f2bf(a3.x); w1.u[5]=f2bf(a3.y); w1.u[6]=f2bf(a3.z); w1.u[7]=f2bf(a3.w);
        ushort8* dst = (ushort8*)&x_lds[row_r * XSTRIDE + row_q * 16];
        dst[0] = w0.u;
        dst[1] = w1.u;

        __syncthreads();

        // ---- MFMA: dot(x_r, p_j) for this wave's 32 j columns ----
        f32x4 acc[2][2];
        f32x4 zero = {0.f, 0.f, 0.f, 0.f};
        acc[0][0]=zero; acc[0][1]=zero; acc[1][0]=zero; acc[1][1]=zero;
#pragma unroll
        for (int kt = 0; kt < 4; ++kt) {
#pragma unroll
            for (int mt = 0; mt < 2; ++mt) {
                FragU af;
                af.u = *(const ushort8*)&x_lds[(mt*16 + l15) * XSTRIDE + kt*32 + quad*8];
                acc[mt][0] = __builtin_amdgcn_mfma_f32_16x16x32_bf16(af.b, bfrag[0][kt].b, acc[mt][0], 0, 0, 0);
                acc[mt][1] = __builtin_amdgcn_mfma_f32_16x16x32_bf16(af.b, bfrag[1][kt].b, acc[mt][1], 0, 0, 0);
            }
        }

        // ---- per-row argmin over this wave's 32 columns ----
#pragma unroll
        for (int mt = 0; mt < 2; ++mt) {
#pragma unroll
            for (int reg = 0; reg < 4; ++reg) {
                float s0 = p2h[0] - acc[mt][0][reg];
                float s1 = p2h[1] - acc[mt][1][reg];
                int j0 = wave*32 + l15, j1 = j0 + 16;
                float sm; int jm;
                if (s1 < s0) { sm = s1; jm = j1; } else { sm = s0; jm = j0; }
#pragma unroll
                for (int mask = 1; mask <= 8; mask <<= 1) {
                    float so = __shfl_xor(sm, mask);
                    int   jo = __shfl_xor(jm, mask);
                    if (so < sm || (so == sm && jo < jm)) { sm = so; jm = jo; }
                }
                if (l15 == 0) {
                    int r = mt*16 + quad*4 + reg;
                    wmin_s[wave][r] = sm;
                    wmin_j[wave][r] = jm;
                }
            }
        }
        __syncthreads();

        // ---- final per-row nll (threads 0..31, all in wave 0) ----
        if (tid < TILE_ROWS) {
            float bs = wmin_s[0][tid]; int bj = wmin_j[0][tid];
#pragma unroll
            for (int w = 1; w < 4; ++w) {
                float s2 = wmin_s[w][tid]; int j2 = wmin_j[w][tid];
                if (s2 < bs) { bs = s2; bj = j2; }   // strict <: ties keep lower j
            }
            int lab = labels[row0 + tid];
            int eff = (lab <= kk - 1) ? lab : bj;
            float xv = bf2f(x_lds[tid * XSTRIDE + eff]);
            nll_acc += lse_lds[tid] - xv;
        }
    }

    // ---- block reduce (only wave-0 threads hold nonzero) + device atomic ----
    if (wave == 0) {
        float v = nll_acc;
#pragma unroll
        for (int mask = 32; mask >= 1; mask >>= 1) v += __shfl_xor(v, mask);
        if (lane == 0) atomicAdd(accum, v);
    }
}

extern "C" __global__ void ploss_finalize(const float* __restrict__ accum,
                                          float* __restrict__ out, float inv_n)
{
    out[0] = accum[0] * inv_n;
}

extern "C" void kernel_launch(void* const* d_in, const int* in_sizes, int n_in,
                              void* d_out, int out_size, void* d_ws, size_t ws_size,
                              hipStream_t stream)
{
    const float* x      = (const float*)d_in[0];
    const int*   labels = (const int*)d_in[1];
    const float* protos = (const float*)d_in[2];
    const int*   kptr   = (const int*)d_in[3];
    const int n_rows  = in_sizes[0] / C_DIM;
    const int n_tiles = n_rows / TILE_ROWS;   // N=400000 -> 12500 exact

    float* accum = (float*)d_ws;
    hipMemsetAsync(accum, 0, sizeof(float), stream);   // ws re-poisoned each call

    int grid = 1024;
    if (grid > n_tiles) grid = n_tiles;
    ploss_main<<<grid, NTHREADS, 0, stream>>>(x, labels, protos, kptr, accum, n_tiles);
    ploss_finalize<<<1, 1, 0, stream>>>(accum, (float*)d_out, 1.0f / (float)n_rows);
}

// Round 2
// 309.591 us; speedup vs baseline: 1.1554x; 1.1554x over previous
//
#include <hip/hip_runtime.h>
#include <hip/hip_bf16.h>

// PLoss fused kernel, round 2.
// Round-1 post-mortem: 157 us, HBM 8%, VALU 25%, Mfma 3.3% -> latency-bound,
// serial per-tile chain (x load -> softmax -> barrier -> mfma -> argmin
// (64 bpermute/thread!) -> barrier -> labels load on critical path).
// Changes this round:
//  - Register double-buffer prefetch of next tile's x + labels at loop top
//    (hides ~900cyc HBM latency under tile body; labels off critical path).
//  - LDS double-buffer for x/lse: 2 barriers/iter instead of 3; wave0 epilogue
//    overlaps other waves' staging.
//  - Packed argmin: order-preserving uint(score) with 7-bit proto index in the
//    low mantissa bits (<=127 ulp perturbation, ~1e-5 rel — min-gap sigma ~9);
//    single u32 min+shfl per step: 32 bpermutes/thread/tile instead of 64,
//    no cmp/cndmask pairs. Tie-break = lowest index, matching jnp.argmin.
//  - grid 2048.

#define C_DIM 128
#define TILE_ROWS 32
#define NTHREADS 256
#define XSTRIDE 136   // bf16 elems per LDS row: 128 + 8 pad (rows 16B-aligned)
#define GRID 2048

typedef __bf16 bf16x8 __attribute__((ext_vector_type(8)));
typedef unsigned short ushort8 __attribute__((ext_vector_type(8)));
typedef float f32x4 __attribute__((ext_vector_type(4)));

union FragU { ushort8 u; bf16x8 b; };

__device__ __forceinline__ unsigned short f2bf(float f) {
    unsigned int u = __float_as_uint(f);
    u += 0x7fffu + ((u >> 16) & 1u);   // round-to-nearest-even
    return (unsigned short)(u >> 16);
}
__device__ __forceinline__ float bf2f(unsigned short h) {
    return __uint_as_float(((unsigned int)h) << 16);
}
// order-preserving float->uint (min-compatible)
__device__ __forceinline__ unsigned f2ord(float s) {
    unsigned u = __float_as_uint(s);
    return (u & 0x80000000u) ? ~u : (u | 0x80000000u);
}

extern "C" __global__ void __launch_bounds__(NTHREADS)
ploss_main(const float* __restrict__ x, const int* __restrict__ labels,
           const float* __restrict__ protos, const int* __restrict__ kptr,
           float* __restrict__ accum, int n_tiles)
{
    __shared__ __attribute__((aligned(16))) unsigned short x_lds[2][TILE_ROWS * XSTRIDE];
    __shared__ float lse_lds[2][TILE_ROWS];
    __shared__ unsigned wmin_u[4][TILE_ROWS];

    const int tid  = threadIdx.x;
    const int lane = tid & 63;
    const int wave = tid >> 6;
    const int l15  = lane & 15;
    const int quad = lane >> 4;
    const int kk   = kptr[0];

    // ---- preload B fragments (protos, bf16) + 0.5*||p||^2 : once per block ----
    FragU bfrag[2][4];
    float p2h[2];
#pragma unroll
    for (int nt = 0; nt < 2; ++nt) {
        const int j = wave * 32 + nt * 16 + l15;
        const float* pr = protos + j * C_DIM;
        float s = 0.f;
#pragma unroll
        for (int c = 0; c < 32; c += 4) {
            float4 v = *(const float4*)(pr + quad * 32 + c);
            s += v.x*v.x + v.y*v.y + v.z*v.z + v.w*v.w;
        }
        s += __shfl_xor(s, 16);
        s += __shfl_xor(s, 32);
        p2h[nt] = 0.5f * s;
#pragma unroll
        for (int kt = 0; kt < 4; ++kt) {
            const float* pp = pr + kt * 32 + quad * 8;
            float4 v0 = *(const float4*)(pp);
            float4 v1 = *(const float4*)(pp + 4);
            FragU f;
            f.u[0]=f2bf(v0.x); f.u[1]=f2bf(v0.y); f.u[2]=f2bf(v0.z); f.u[3]=f2bf(v0.w);
            f.u[4]=f2bf(v1.x); f.u[5]=f2bf(v1.y); f.u[6]=f2bf(v1.z); f.u[7]=f2bf(v1.w);
            bfrag[nt][kt] = f;
        }
    }

    const int row_r = tid >> 3;   // 0..31: row within tile
    const int row_q = tid & 7;    // 0..7 : 16-elem chunk within row

    float nll_acc = 0.f;
    int p = 0;

    // ---- prologue: load tile t0 into registers ----
    int t = blockIdx.x;
    float4 a0, a1, a2, a3;
    int lab = 0;
    {
        const float* xr = x + ((long long)t * TILE_ROWS + row_r) * C_DIM + row_q * 16;
        a0 = *(const float4*)(xr);
        a1 = *(const float4*)(xr + 4);
        a2 = *(const float4*)(xr + 8);
        a3 = *(const float4*)(xr + 12);
        if (tid < TILE_ROWS) lab = labels[(long long)t * TILE_ROWS + tid];
    }

    for (; t < n_tiles; t += GRID) {
        // ---- prefetch next tile (x + labels) into shadow registers ----
        const int tn = t + GRID;
        const int tl = (tn < n_tiles) ? tn : t;   // clamp: tail load discarded
        float4 b0, b1, b2, b3;
        int labn = 0;
        {
            const float* xr = x + ((long long)tl * TILE_ROWS + row_r) * C_DIM + row_q * 16;
            b0 = *(const float4*)(xr);
            b1 = *(const float4*)(xr + 4);
            b2 = *(const float4*)(xr + 8);
            b3 = *(const float4*)(xr + 12);
            if (tid < TILE_ROWS) labn = labels[(long long)tl * TILE_ROWS + tid];
        }

        // ---- softmax stats from current registers ----
        float m = fmaxf(fmaxf(fmaxf(a0.x,a0.y),fmaxf(a0.z,a0.w)),
                        fmaxf(fmaxf(a1.x,a1.y),fmaxf(a1.z,a1.w)));
        m = fmaxf(m, fmaxf(fmaxf(fmaxf(a2.x,a2.y),fmaxf(a2.z,a2.w)),
                           fmaxf(fmaxf(a3.x,a3.y),fmaxf(a3.z,a3.w))));
        float s = __expf(a0.x-m)+__expf(a0.y-m)+__expf(a0.z-m)+__expf(a0.w-m)
                + __expf(a1.x-m)+__expf(a1.y-m)+__expf(a1.z-m)+__expf(a1.w-m)
                + __expf(a2.x-m)+__expf(a2.y-m)+__expf(a2.z-m)+__expf(a2.w-m)
                + __expf(a3.x-m)+__expf(a3.y-m)+__expf(a3.z-m)+__expf(a3.w-m);
#pragma unroll
        for (int mask = 1; mask <= 4; mask <<= 1) {
            float mo = __shfl_xor(m, mask);
            float so = __shfl_xor(s, mask);
            float nm = fmaxf(m, mo);
            s = s * __expf(m - nm) + so * __expf(mo - nm);
            m = nm;
        }
        if (row_q == 0) lse_lds[p][row_r] = m + __logf(s);

        // ---- bf16 convert -> LDS (buffer p) ----
        FragU w0, w1;
        w0.u[0]=f2bf(a0.x); w0.u[1]=f2bf(a0.y); w0.u[2]=f2bf(a0.z); w0.u[3]=f2bf(a0.w);
        w0.u[4]=f2bf(a1.x); w0.u[5]=f2bf(a1.y); w0.u[6]=f2bf(a1.z); w0.u[7]=f2bf(a1.w);
        w1.u[0]=f2bf(a2.x); w1.u[1]=f2bf(a2.y); w1.u[2]=f2bf(a2.z); w1.u[3]=f2bf(a2.w);
        w1.u[4]=f2bf(a3.x); w1.u[5]=f2bf(a3.y); w1.u[6]=f2bf(a3.z); w1.u[7]=f2bf(a3.w);
        ushort8* dst = (ushort8*)&x_lds[p][row_r * XSTRIDE + row_q * 16];
        dst[0] = w0.u;
        dst[1] = w1.u;

        __syncthreads();

        // ---- MFMA: dot(x_r, p_j) for this wave's 32 j columns ----
        f32x4 acc[2][2];
        f32x4 zero = {0.f, 0.f, 0.f, 0.f};
        acc[0][0]=zero; acc[0][1]=zero; acc[1][0]=zero; acc[1][1]=zero;
#pragma unroll
        for (int kt = 0; kt < 4; ++kt) {
#pragma unroll
            for (int mt = 0; mt < 2; ++mt) {
                FragU af;
                af.u = *(const ushort8*)&x_lds[p][(mt*16 + l15) * XSTRIDE + kt*32 + quad*8];
                acc[mt][0] = __builtin_amdgcn_mfma_f32_16x16x32_bf16(af.b, bfrag[0][kt].b, acc[mt][0], 0, 0, 0);
                acc[mt][1] = __builtin_amdgcn_mfma_f32_16x16x32_bf16(af.b, bfrag[1][kt].b, acc[mt][1], 0, 0, 0);
            }
        }

        // ---- packed per-row argmin over this wave's 32 columns ----
        const unsigned j0 = (unsigned)(wave*32 + l15);
#pragma unroll
        for (int mt = 0; mt < 2; ++mt) {
#pragma unroll
            for (int reg = 0; reg < 4; ++reg) {
                unsigned u0 = (f2ord(p2h[0] - acc[mt][0][reg]) & 0xFFFFFF80u) | j0;
                unsigned u1 = (f2ord(p2h[1] - acc[mt][1][reg]) & 0xFFFFFF80u) | (j0 + 16u);
                unsigned u = u0 < u1 ? u0 : u1;
#pragma unroll
                for (int mask = 1; mask <= 8; mask <<= 1) {
                    unsigned uo = __shfl_xor(u, mask);
                    u = uo < u ? uo : u;
                }
                if (l15 == 0) wmin_u[wave][mt*16 + quad*4 + reg] = u;
            }
        }
        __syncthreads();

        // ---- epilogue: per-row nll (threads 0..31, all wave 0) ----
        if (tid < TILE_ROWS) {
            unsigned u = wmin_u[0][tid];
            unsigned u1 = wmin_u[1][tid]; u = u1 < u ? u1 : u;
            unsigned u2 = wmin_u[2][tid]; u = u2 < u ? u2 : u;
            unsigned u3 = wmin_u[3][tid]; u = u3 < u ? u3 : u;
            const int bj = (int)(u & 127u);
            const int eff = (lab <= kk - 1) ? lab : bj;
            const float xv = bf2f(x_lds[p][tid * XSTRIDE + eff]);
            nll_acc += lse_lds[p][tid] - xv;
        }

        // rotate buffers
        a0 = b0; a1 = b1; a2 = b2; a3 = b3; lab = labn;
        p ^= 1;
    }

    // ---- block reduce (only wave-0 threads hold nonzero) + device atomic ----
    if (wave == 0) {
        float v = nll_acc;
#pragma unroll
        for (int mask = 32; mask >= 1; mask >>= 1) v += __shfl_xor(v, mask);
        if (lane == 0) atomicAdd(accum, v);
    }
}

extern "C" __global__ void ploss_finalize(const float* __restrict__ accum,
                                          float* __restrict__ out, float inv_n)
{
    out[0] = accum[0] * inv_n;
}

extern "C" void kernel_launch(void* const* d_in, const int* in_sizes, int n_in,
                              void* d_out, int out_size, void* d_ws, size_t ws_size,
                              hipStream_t stream)
{
    const float* x      = (const float*)d_in[0];
    const int*   labels = (const int*)d_in[1];
    const float* protos = (const float*)d_in[2];
    const int*   kptr   = (const int*)d_in[3];
    const int n_rows  = in_sizes[0] / C_DIM;
    const int n_tiles = n_rows / TILE_ROWS;   // N=400000 -> 12500 exact

    float* accum = (float*)d_ws;
    hipMemsetAsync(accum, 0, sizeof(float), stream);   // ws re-poisoned each call

    int grid = GRID;
    if (grid > n_tiles) grid = n_tiles;
    ploss_main<<<grid, NTHREADS, 0, stream>>>(x, labels, protos, kptr, accum, n_tiles);
    ploss_finalize<<<1, 1, 0, stream>>>(accum, (float*)d_out, 1.0f / (float)n_rows);
}